// Round 7
// baseline (97.077 us; speedup 1.0000x reference)
//
#include <hip/hip_runtime.h>
#include <math.h>

#define NROI 5000
#define NCLS 81
#define MIN_CONF_F 0.7f
#define MAX_INST_I 100
#define NMS_THR_F 0.3f
#define CAP2 128          // per-class cap (~8.5 sigma above Binomial(5000,1/81) mean 61.7)
#define SLOT 128          // survivor slots per class
#define HBINS 2048
#define CAPF 512          // candidate cap for final top-100
#define BMIN 0x3F333      // (bits of 0.7f) >> 12; scores in [0.7,1) -> bins [0,1229)

// ---------------- K1: per-ROI refine, one wave per ROI (5000 waves) ----------------
__global__ __launch_bounds__(256) void det_stage1(
    const float* __restrict__ rois, const float* __restrict__ probs,
    const float* __restrict__ deltas, const float* __restrict__ window,
    float4* __restrict__ g_box, float* __restrict__ g_score,
    int* __restrict__ g_cid, unsigned int* __restrict__ ctrl)
{
  const int gtid = blockIdx.x * blockDim.x + threadIdx.x;
  if (gtid == 0) ctrl[0] = 0u;    // ticket counter for K2 (kernel boundary publishes)
  const int i = gtid >> 6;        // ROI = global wave id
  const int lane = threadIdx.x & 63;
  if (i >= NROI) return;
  const float* p = probs + (size_t)i * NCLS;
  float v0 = p[lane];             // classes 0..63 (coalesced)
  unsigned long long key =
      ((unsigned long long)__float_as_uint(v0) << 32) | (unsigned)(255 - lane);
  if (lane < NCLS - 64) {         // classes 64..80
    float v1 = p[64 + lane];
    unsigned long long k1 =
        ((unsigned long long)__float_as_uint(v1) << 32) | (unsigned)(255 - (64 + lane));
    if (k1 > key) key = k1;
  }
  #pragma unroll
  for (int off = 32; off > 0; off >>= 1) {
    unsigned long long o = __shfl_xor(key, off, 64);
    if (o > key) key = o;
  }
  if (lane == 0) {
    int bc = 255 - (int)(key & 0xFFull);
    float best = __uint_as_float((unsigned)(key >> 32));
    const float* d = deltas + ((size_t)i * NCLS + bc) * 4;
    float dy = d[0]*0.1f, dx = d[1]*0.1f, dh = d[2]*0.2f, dwv = d[3]*0.2f;
    float y1 = rois[i*4+0], x1 = rois[i*4+1], y2 = rois[i*4+2], x2 = rois[i*4+3];
    float h = y2 - y1, w = x2 - x1;
    float cy = y1 + 0.5f*h, cx = x1 + 0.5f*w;
    cy = cy + dy*h; cx = cx + dx*w;
    h = h*expf(dh); w = w*expf(dwv);
    float ny1 = cy - 0.5f*h, nx1 = cx - 0.5f*w;
    float ny2 = ny1 + h, nx2 = nx1 + w;
    float wy1 = window[0], wx1 = window[1], wy2 = window[2], wx2 = window[3];
    ny1 = fminf(fmaxf(ny1, wy1), wy2);
    nx1 = fminf(fmaxf(nx1, wx1), wx2);
    ny2 = fminf(fmaxf(ny2, wy1), wy2);
    nx2 = fminf(fmaxf(nx2, wx1), wx2);
    g_box[i] = make_float4(ny1, nx1, ny2, nx2);
    g_score[i] = best;
    g_cid[i] = (bc > 0 && best >= MIN_CONF_F) ? bc : -1;   // -1 == invalid
  }
}

// ---------------- K2: per-class mask-NMS + last-done-block top-100 ----------------
__global__ __launch_bounds__(1024) void det_nms_topk(
    const float4* __restrict__ g_box, const float* __restrict__ g_score,
    const int* __restrict__ g_cid, unsigned int* __restrict__ ctrl,
    int* __restrict__ svc, unsigned long long* __restrict__ skeys,
    float4* __restrict__ sboxes, float* __restrict__ out)
{
  const int c = blockIdx.x + 1;   // class 1..80
  const int tid = threadIdx.x;
  const int lane = tid & 63, wv = tid >> 6;
  __shared__ int scnt;
  __shared__ unsigned long long keys[CAP2], skey[CAP2];
  __shared__ float by1[CAP2], bx1[CAP2], by2[CAP2], bx2[CAP2], barea[CAP2];
  __shared__ unsigned int mask[CAP2][4];
  __shared__ unsigned int keepw[4];
  __shared__ int sticket;
  if (tid == 0) scnt = 0;
  for (int q = tid; q < CAP2 * 4; q += 1024) ((unsigned int*)mask)[q] = 0u;
  __syncthreads();
  // collection: stream cid4 + score4 unconditionally (no load->atomic->load chain)
  const int4* cid4 = (const int4*)g_cid;
  const float4* sc4 = (const float4*)g_score;
  for (int v = tid; v < NROI / 4; v += 1024) {
    int4 cv = cid4[v];
    float4 sv = sc4[v];
    int base = v * 4;
    #pragma unroll
    for (int q = 0; q < 4; ++q) {
      int cq = (q == 0) ? cv.x : (q == 1) ? cv.y : (q == 2) ? cv.z : cv.w;
      float sq = (q == 0) ? sv.x : (q == 1) ? sv.y : (q == 2) ? sv.z : sv.w;
      if (cq == c) {
        int pos = atomicAdd(&scnt, 1);
        if (pos < CAP2)
          keys[pos] = ((unsigned long long)__float_as_uint(sq) << 32) |
                      (unsigned int)(0xFFFFFFFFu - (unsigned int)(base + q));
      }
    }
  }
  __syncthreads();
  int cnt = scnt < CAP2 ? scnt : CAP2;
  if (cnt > 0) {
    // rank-selection sort (keys unique): r = #greater -> skey[r]
    if (tid < cnt) {
      unsigned long long mk = keys[tid];
      int r = 0;
      for (int q = 0; q < cnt; ++q) r += (keys[q] > mk) ? 1 : 0;
      skey[r] = mk;
    }
    __syncthreads();
    if (tid < cnt) {
      int idx = (int)(0xFFFFFFFFu - (unsigned)(skey[tid] & 0xFFFFFFFFull));
      float4 b = g_box[idx];
      by1[tid] = b.x; bx1[tid] = b.y; by2[tid] = b.z; bx2[tid] = b.w;
      barea[tid] = fmaxf(b.z - b.x, 0.0f) * fmaxf(b.w - b.y, 0.0f);
    }
    __syncthreads();
    // pair-parallel IoU -> suppression bitmasks (bit k set in row j, k>j)
    int m = 1, lg = 0;
    while (m < cnt) { m <<= 1; ++lg; }
    int tot = m * m;
    for (int p = tid; p < tot; p += 1024) {
      int j = p >> lg, k = p & (m - 1);
      if (k > j && k < cnt) {
        float iy1 = fmaxf(by1[j], by1[k]);
        float ix1 = fmaxf(bx1[j], bx1[k]);
        float iy2 = fminf(by2[j], by2[k]);
        float ix2 = fminf(bx2[j], bx2[k]);
        float inter = fmaxf(iy2 - iy1, 0.0f) * fmaxf(ix2 - ix1, 0.0f);
        float uni = barea[j] + barea[k] - inter;
        float iou = (uni > 0.0f) ? inter / fmaxf(uni, 1e-12f) : 0.0f;
        if (iou > NMS_THR_F) atomicOr(&mask[j][k >> 5], 1u << (k & 31));
      }
    }
  }
  __syncthreads();
  // wave-0 register/shuffle greedy resolve (no LDS in the carry chain)
  if (tid < 64) {
    unsigned long long row_lo = 0, row_hi = 0, row2_lo = 0, row2_hi = 0;
    if (tid < cnt) {
      row_lo = (unsigned long long)mask[tid][0] | ((unsigned long long)mask[tid][1] << 32);
      row_hi = (unsigned long long)mask[tid][2] | ((unsigned long long)mask[tid][3] << 32);
    }
    if (tid + 64 < cnt) {
      row2_lo = (unsigned long long)mask[tid+64][0] | ((unsigned long long)mask[tid+64][1] << 32);
      row2_hi = (unsigned long long)mask[tid+64][2] | ((unsigned long long)mask[tid+64][3] << 32);
    }
    unsigned long long sup_lo = 0, sup_hi = 0, keep_lo = 0, keep_hi = 0;
    int kc = 0;
    for (int j = 0; j < cnt; ++j) {
      bool s = (j < 64) ? (((sup_lo >> j) & 1ull) != 0)
                        : (((sup_hi >> (j - 64)) & 1ull) != 0);
      if (!s && kc < MAX_INST_I) {
        if (j < 64) keep_lo |= 1ull << j; else keep_hi |= 1ull << (j - 64);
        ++kc;
        unsigned long long rl = (j < 64) ? row_lo : row2_lo;
        unsigned long long rh = (j < 64) ? row_hi : row2_hi;
        rl = __shfl(rl, j & 63, 64);
        rh = __shfl(rh, j & 63, 64);
        sup_lo |= rl; sup_hi |= rh;
      }
    }
    if (tid == 0) {
      keepw[0] = (unsigned)keep_lo; keepw[1] = (unsigned)(keep_lo >> 32);
      keepw[2] = (unsigned)keep_hi; keepw[3] = (unsigned)(keep_hi >> 32);
      svc[c - 1] = kc;              // ALWAYS written (0 when cnt==0)
    }
  }
  __syncthreads();
  // survivors -> fixed per-class slots, ordered by keep rank (plain stores)
  if (tid < cnt) {
    unsigned long long klo = (unsigned long long)keepw[0] | ((unsigned long long)keepw[1] << 32);
    unsigned long long khi = (unsigned long long)keepw[2] | ((unsigned long long)keepw[3] << 32);
    bool kept = (tid < 64) ? ((klo >> tid) & 1ull) : ((khi >> (tid - 64)) & 1ull);
    if (kept) {
      int order = (tid < 64)
        ? __popcll(klo & ((1ull << tid) - 1ull))
        : __popcll(klo) + __popcll(khi & ((1ull << (tid - 64)) - 1ull));
      int slot = ((c - 1) << 7) + order;
      skeys[slot] = skey[tid];
      sboxes[slot] = make_float4(by1[tid], bx1[tid], by2[tid], bx2[tid]);
    }
  }
  __syncthreads();
  // last-done-block handoff (deadlock-free; stale-ctrl solo replay just skips)
  if (tid == 0) {
    __threadfence();                       // release: publish svc/skeys/sboxes
    sticket = (int)atomicAdd(&ctrl[0], 1u);
  }
  __syncthreads();
  if (sticket != NCLS - 2) return;         // 80 blocks -> last ticket is 79
  __threadfence();                         // acquire: invalidate stale lines

  // ---------------- phase C: top-100 over survivor slots ----------------
  __shared__ int svcnt[80];
  __shared__ int hist[HBINS];
  __shared__ unsigned long long cand[CAPF];
  __shared__ int cslot[CAPF];
  __shared__ float orows[6 * MAX_INST_I];
  __shared__ int wsum[16];
  __shared__ int fcnt, sR;
  if (tid < 80) svcnt[tid] = svc[tid];
  for (int b = tid; b < HBINS; b += 1024) hist[b] = 0;
  if (tid == 0) { fcnt = 0; sR = 1 << 30; }
  if (tid < 6 * MAX_INST_I) orows[tid] = 0.0f;
  __syncthreads();
  // histogram survivor scores (bits monotonic for positive floats)
  for (int s = tid; s < 80 * SLOT; s += 1024) {
    int cc = s >> 7, k = s & (SLOT - 1);
    if (k < svcnt[cc]) {
      unsigned int bits = (unsigned int)(skeys[s] >> 32);
      int b = (int)(bits >> 12) - BMIN;
      b = b < 0 ? 0 : (b > HBINS - 1 ? HBINS - 1 : b);
      atomicAdd(&hist[b], 1);
    }
  }
  __syncthreads();
  // suffix-count threshold: thread t owns rev positions 2t,2t+1 (bin HBINS-1-r)
  int a0 = hist[HBINS - 1 - 2 * tid];
  int a1 = hist[HBINS - 2 - 2 * tid];
  int val = a0 + a1;
  int incl = val;
  #pragma unroll
  for (int off = 1; off < 64; off <<= 1) {
    int nn = __shfl_up(incl, off, 64);
    if (lane >= off) incl += nn;
  }
  if (lane == 63) wsum[wv] = incl;
  __syncthreads();
  if (tid == 0) { int s = 0; for (int q = 0; q < 16; ++q) { s += wsum[q]; wsum[q] = s; } }
  __syncthreads();
  incl += (wv > 0) ? wsum[wv - 1] : 0;
  int excl = incl - val;
  if (excl + a0 >= MAX_INST_I) atomicMin(&sR, 2 * tid);
  else if (incl >= MAX_INST_I) atomicMin(&sR, 2 * tid + 1);
  __syncthreads();
  const int T = (sR >= HBINS) ? 0 : (HBINS - 1 - sR);   // total<100 -> collect all
  // collect candidates in bins >= T (contains the top-100)
  for (int s = tid; s < 80 * SLOT; s += 1024) {
    int cc = s >> 7, k = s & (SLOT - 1);
    if (k < svcnt[cc]) {
      unsigned long long key = skeys[s];
      unsigned int bits = (unsigned int)(key >> 32);
      int b = (int)(bits >> 12) - BMIN;
      b = b < 0 ? 0 : (b > HBINS - 1 ? HBINS - 1 : b);
      if (b >= T) {
        int pos = atomicAdd(&fcnt, 1);
        if (pos < CAPF) { cand[pos] = key; cslot[pos] = s; }
      }
    }
  }
  __syncthreads();
  int fc = fcnt < CAPF ? fcnt : CAPF;
  // rank placement (keys unique -> exact descending permutation)
  if (tid < fc) {
    unsigned long long mk = cand[tid];
    int r = 0;
    for (int q = 0; q < fc; ++q) r += (cand[q] > mk) ? 1 : 0;
    if (r < MAX_INST_I) {
      int slot = cslot[tid];
      float4 b = sboxes[slot];
      orows[r * 6 + 0] = b.x;
      orows[r * 6 + 1] = b.y;
      orows[r * 6 + 2] = b.z;
      orows[r * 6 + 3] = b.w;
      orows[r * 6 + 4] = (float)((slot >> 7) + 1);
      orows[r * 6 + 5] = __uint_as_float((unsigned int)(mk >> 32));
    }
  }
  __syncthreads();
  if (tid < 6 * MAX_INST_I) out[tid] = orows[tid];
}

extern "C" void kernel_launch(void* const* d_in, const int* in_sizes, int n_in,
                              void* d_out, int out_size, void* d_ws, size_t ws_size,
                              hipStream_t stream)
{
  const float* rois   = (const float*)d_in[0];
  const float* probs  = (const float*)d_in[1];
  const float* deltas = (const float*)d_in[2];
  const float* window = (const float*)d_in[3];
  float* out = (float*)d_out;

  char* ws = (char*)d_ws;
  float4* g_box   = (float4*)ws;                              // 80,000 B
  float*  g_score = (float*)(ws + 80000);                     // 20,000 B (16B-aligned)
  int*    g_cid   = (int*)(ws + 100000);                      // 20,000 B (16B-aligned)
  unsigned int* ctrl = (unsigned int*)(ws + 120000);          // 64 B  {ticket}
  int*    svc     = (int*)(ws + 120064);                      // 320 B
  unsigned long long* skeys = (unsigned long long*)(ws + 120448);   // 80*128*8 = 81,920 B
  float4* sboxes  = (float4*)(ws + 202368);                   // 80*128*16 = 163,840 B

  det_stage1<<<(NROI * 64 + 255) / 256, 256, 0, stream>>>(
      rois, probs, deltas, window, g_box, g_score, g_cid, ctrl);
  det_nms_topk<<<NCLS - 1, 1024, 0, stream>>>(
      g_box, g_score, g_cid, ctrl, svc, skeys, sboxes, out);
}

// Round 9
// 94.797 us; speedup vs baseline: 1.0240x; 1.0240x over previous
//
#include <hip/hip_runtime.h>
#include <math.h>

#define NROI 5000
#define NCLS 81
#define MIN_CONF_F 0.7f
#define MAX_INST_I 100
#define NMS_THR_F 0.3f
#define CAP2 128          // per-class cap (~8.5 sigma above Binomial(5000,1/81) mean 61.7)
#define SLOT 128          // survivor slots per class
#define HBINS 2048
#define CAPF 512          // candidate cap for final top-100
#define BMIN 0x3F333      // (bits of 0.7f) >> 12; scores in [0.7,1) -> bins [0,1229)

// ---------------- K1: per-ROI refine, one wave per ROI (5000 waves) ----------------
__global__ __launch_bounds__(256) void det_stage1(
    const float* __restrict__ rois, const float* __restrict__ probs,
    const float* __restrict__ deltas, const float* __restrict__ window,
    float4* __restrict__ g_box, float* __restrict__ g_score,
    int* __restrict__ g_cid)
{
  const int gtid = blockIdx.x * blockDim.x + threadIdx.x;
  const int i = gtid >> 6;        // ROI = global wave id
  const int lane = threadIdx.x & 63;
  if (i >= NROI) return;
  const float* p = probs + (size_t)i * NCLS;
  float v0 = p[lane];             // classes 0..63 (coalesced)
  unsigned long long key =
      ((unsigned long long)__float_as_uint(v0) << 32) | (unsigned)(255 - lane);
  if (lane < NCLS - 64) {         // classes 64..80
    float v1 = p[64 + lane];
    unsigned long long k1 =
        ((unsigned long long)__float_as_uint(v1) << 32) | (unsigned)(255 - (64 + lane));
    if (k1 > key) key = k1;
  }
  #pragma unroll
  for (int off = 32; off > 0; off >>= 1) {
    unsigned long long o = __shfl_xor(key, off, 64);
    if (o > key) key = o;
  }
  if (lane == 0) {
    int bc = 255 - (int)(key & 0xFFull);
    float best = __uint_as_float((unsigned)(key >> 32));
    const float* d = deltas + ((size_t)i * NCLS + bc) * 4;
    float dy = d[0]*0.1f, dx = d[1]*0.1f, dh = d[2]*0.2f, dwv = d[3]*0.2f;
    float y1 = rois[i*4+0], x1 = rois[i*4+1], y2 = rois[i*4+2], x2 = rois[i*4+3];
    float h = y2 - y1, w = x2 - x1;
    float cy = y1 + 0.5f*h, cx = x1 + 0.5f*w;
    cy = cy + dy*h; cx = cx + dx*w;
    h = h*expf(dh); w = w*expf(dwv);
    float ny1 = cy - 0.5f*h, nx1 = cx - 0.5f*w;
    float ny2 = ny1 + h, nx2 = nx1 + w;
    float wy1 = window[0], wx1 = window[1], wy2 = window[2], wx2 = window[3];
    ny1 = fminf(fmaxf(ny1, wy1), wy2);
    nx1 = fminf(fmaxf(nx1, wx1), wx2);
    ny2 = fminf(fmaxf(ny2, wy1), wy2);
    nx2 = fminf(fmaxf(nx2, wx1), wx2);
    g_box[i] = make_float4(ny1, nx1, ny2, nx2);
    g_score[i] = best;
    g_cid[i] = (bc > 0 && best >= MIN_CONF_F) ? bc : -1;   // -1 == invalid
  }
}

// ---------------- K2: per-class mask-NMS, zero-filled fixed-slot output ----------------
// ALL SLOT slots per class are written every run: survivors (in keep order) at
// [0,kc), zeros at [kc,SLOT). Valid keys are nonzero (score bits >= 0x3F333333),
// so key != 0 <=> valid survivor. Inverse map rankpos[] avoids the R8 hole where
// a kept thread with tid >= kc left its own slot unwritten.
__global__ __launch_bounds__(1024) void det_nms(
    const float4* __restrict__ g_box, const float* __restrict__ g_score,
    const int* __restrict__ g_cid,
    unsigned long long* __restrict__ skeys, float4* __restrict__ sboxes)
{
  const int c = blockIdx.x + 1;   // class 1..80
  const int tid = threadIdx.x;
  __shared__ int scnt;
  __shared__ unsigned long long keys[CAP2], skey[CAP2];
  __shared__ float by1[CAP2], bx1[CAP2], by2[CAP2], bx2[CAP2], barea[CAP2];
  __shared__ unsigned int mask[CAP2][4];
  __shared__ unsigned int keepw[4];
  __shared__ unsigned char rankpos[SLOT];   // keep-rank -> sorted position
  if (tid == 0) scnt = 0;
  for (int q = tid; q < CAP2 * 4; q += 1024) ((unsigned int*)mask)[q] = 0u;
  __syncthreads();
  // collection: stream cid4 + score4 unconditionally (no load->atomic->load chain)
  const int4* cid4 = (const int4*)g_cid;
  const float4* sc4 = (const float4*)g_score;
  for (int v = tid; v < NROI / 4; v += 1024) {
    int4 cv = cid4[v];
    float4 sv = sc4[v];
    int base = v * 4;
    #pragma unroll
    for (int q = 0; q < 4; ++q) {
      int cq = (q == 0) ? cv.x : (q == 1) ? cv.y : (q == 2) ? cv.z : cv.w;
      float sq = (q == 0) ? sv.x : (q == 1) ? sv.y : (q == 2) ? sv.z : sv.w;
      if (cq == c) {
        int pos = atomicAdd(&scnt, 1);
        if (pos < CAP2)
          keys[pos] = ((unsigned long long)__float_as_uint(sq) << 32) |
                      (unsigned int)(0xFFFFFFFFu - (unsigned int)(base + q));
      }
    }
  }
  __syncthreads();
  int cnt = scnt < CAP2 ? scnt : CAP2;
  if (cnt > 0) {
    // rank-selection sort (keys unique): r = #greater -> skey[r]
    if (tid < cnt) {
      unsigned long long mk = keys[tid];
      int r = 0;
      for (int q = 0; q < cnt; ++q) r += (keys[q] > mk) ? 1 : 0;
      skey[r] = mk;
    }
    __syncthreads();
    if (tid < cnt) {
      int idx = (int)(0xFFFFFFFFu - (unsigned)(skey[tid] & 0xFFFFFFFFull));
      float4 b = g_box[idx];
      by1[tid] = b.x; bx1[tid] = b.y; by2[tid] = b.z; bx2[tid] = b.w;
      barea[tid] = fmaxf(b.z - b.x, 0.0f) * fmaxf(b.w - b.y, 0.0f);
    }
    __syncthreads();
    // pair-parallel IoU -> suppression bitmasks (bit k set in row j, k>j)
    int m = 1, lg = 0;
    while (m < cnt) { m <<= 1; ++lg; }
    int tot = m * m;
    for (int p = tid; p < tot; p += 1024) {
      int j = p >> lg, k = p & (m - 1);
      if (k > j && k < cnt) {
        float iy1 = fmaxf(by1[j], by1[k]);
        float ix1 = fmaxf(bx1[j], bx1[k]);
        float iy2 = fminf(by2[j], by2[k]);
        float ix2 = fminf(bx2[j], bx2[k]);
        float inter = fmaxf(iy2 - iy1, 0.0f) * fmaxf(ix2 - ix1, 0.0f);
        float uni = barea[j] + barea[k] - inter;
        float iou = (uni > 0.0f) ? inter / fmaxf(uni, 1e-12f) : 0.0f;
        if (iou > NMS_THR_F) atomicOr(&mask[j][k >> 5], 1u << (k & 31));
      }
    }
  }
  __syncthreads();
  // wave-0 register/shuffle greedy resolve (no LDS in the carry chain)
  if (tid < 64) {
    unsigned long long row_lo = 0, row_hi = 0, row2_lo = 0, row2_hi = 0;
    if (tid < cnt) {
      row_lo = (unsigned long long)mask[tid][0] | ((unsigned long long)mask[tid][1] << 32);
      row_hi = (unsigned long long)mask[tid][2] | ((unsigned long long)mask[tid][3] << 32);
    }
    if (tid + 64 < cnt) {
      row2_lo = (unsigned long long)mask[tid+64][0] | ((unsigned long long)mask[tid+64][1] << 32);
      row2_hi = (unsigned long long)mask[tid+64][2] | ((unsigned long long)mask[tid+64][3] << 32);
    }
    unsigned long long sup_lo = 0, sup_hi = 0, keep_lo = 0, keep_hi = 0;
    int kc = 0;
    for (int j = 0; j < cnt; ++j) {
      bool s = (j < 64) ? (((sup_lo >> j) & 1ull) != 0)
                        : (((sup_hi >> (j - 64)) & 1ull) != 0);
      if (!s && kc < MAX_INST_I) {
        if (j < 64) keep_lo |= 1ull << j; else keep_hi |= 1ull << (j - 64);
        ++kc;
        unsigned long long rl = (j < 64) ? row_lo : row2_lo;
        unsigned long long rh = (j < 64) ? row_hi : row2_hi;
        rl = __shfl(rl, j & 63, 64);
        rh = __shfl(rh, j & 63, 64);
        sup_lo |= rl; sup_hi |= rh;
      }
    }
    if (tid == 0) {
      keepw[0] = (unsigned)keep_lo; keepw[1] = (unsigned)(keep_lo >> 32);
      keepw[2] = (unsigned)keep_hi; keepw[3] = (unsigned)(keep_hi >> 32);
    }
  }
  __syncthreads();
  // build inverse map: keep-rank -> sorted position
  {
    unsigned long long klo = (unsigned long long)keepw[0] | ((unsigned long long)keepw[1] << 32);
    unsigned long long khi = (unsigned long long)keepw[2] | ((unsigned long long)keepw[3] << 32);
    if (tid < cnt) {
      bool kept = (tid < 64) ? ((klo >> tid) & 1ull) : ((khi >> (tid - 64)) & 1ull);
      if (kept) {
        int order = (tid < 64)
          ? __popcll(klo & ((1ull << tid) - 1ull))
          : __popcll(klo) + __popcll(khi & ((1ull << (tid - 64)) - 1ull));
        rankpos[order] = (unsigned char)tid;
      }
    }
    __syncthreads();
    // every slot written exactly once: survivors at [0,kc), zeros at [kc,SLOT)
    if (tid < SLOT) {
      int kc = __popcll(klo) + __popcll(khi);
      int base = (c - 1) << 7;
      if (tid < kc) {
        int src = rankpos[tid];
        skeys[base + tid] = skey[src];
        sboxes[base + tid] = make_float4(by1[src], bx1[src], by2[src], bx2[src]);
      } else {
        skeys[base + tid] = 0ull;
      }
    }
  }
}

// ---------------- K3: top-100 over survivor slots (key!=0 == valid) ----------------
__global__ __launch_bounds__(1024) void det_topk(
    const unsigned long long* __restrict__ skeys,
    const float4* __restrict__ sboxes, float* __restrict__ out)
{
  const int tid = threadIdx.x;
  const int lane = tid & 63, wv = tid >> 6;
  __shared__ int hist[HBINS];
  __shared__ unsigned long long cand[CAPF];
  __shared__ int cslot[CAPF];
  __shared__ float orows[6 * MAX_INST_I];
  __shared__ int wsum[16];
  __shared__ int fcnt, sR;
  for (int b = tid; b < HBINS; b += 1024) hist[b] = 0;
  if (tid == 0) { fcnt = 0; sR = 1 << 30; }
  if (tid < 6 * MAX_INST_I) orows[tid] = 0.0f;
  __syncthreads();
  // histogram survivor scores: unconditional streaming, no dependent count load
  for (int s = tid; s < 80 * SLOT; s += 1024) {      // 10 independent iterations
    unsigned long long key = skeys[s];
    if (key != 0ull) {
      unsigned int bits = (unsigned int)(key >> 32);
      int b = (int)(bits >> 12) - BMIN;
      b = b < 0 ? 0 : (b > HBINS - 1 ? HBINS - 1 : b);
      atomicAdd(&hist[b], 1);
    }
  }
  __syncthreads();
  // suffix-count threshold: thread t owns rev positions 2t,2t+1 (bin HBINS-1-r)
  int a0 = hist[HBINS - 1 - 2 * tid];
  int a1 = hist[HBINS - 2 - 2 * tid];
  int val = a0 + a1;
  int incl = val;
  #pragma unroll
  for (int off = 1; off < 64; off <<= 1) {
    int nn = __shfl_up(incl, off, 64);
    if (lane >= off) incl += nn;
  }
  if (lane == 63) wsum[wv] = incl;
  __syncthreads();
  if (tid == 0) { int s = 0; for (int q = 0; q < 16; ++q) { s += wsum[q]; wsum[q] = s; } }
  __syncthreads();
  incl += (wv > 0) ? wsum[wv - 1] : 0;
  int excl = incl - val;
  if (excl + a0 >= MAX_INST_I) atomicMin(&sR, 2 * tid);
  else if (incl >= MAX_INST_I) atomicMin(&sR, 2 * tid + 1);
  __syncthreads();
  const int T = (sR >= HBINS) ? 0 : (HBINS - 1 - sR);   // total<100 -> collect all
  // collect candidates in bins >= T (contains the top-100)
  for (int s = tid; s < 80 * SLOT; s += 1024) {
    unsigned long long key = skeys[s];
    if (key != 0ull) {
      unsigned int bits = (unsigned int)(key >> 32);
      int b = (int)(bits >> 12) - BMIN;
      b = b < 0 ? 0 : (b > HBINS - 1 ? HBINS - 1 : b);
      if (b >= T) {
        int pos = atomicAdd(&fcnt, 1);
        if (pos < CAPF) { cand[pos] = key; cslot[pos] = s; }
      }
    }
  }
  __syncthreads();
  int fc = fcnt < CAPF ? fcnt : CAPF;
  // rank placement (keys unique -> exact descending permutation)
  if (tid < fc) {
    unsigned long long mk = cand[tid];
    int r = 0;
    for (int q = 0; q < fc; ++q) r += (cand[q] > mk) ? 1 : 0;
    if (r < MAX_INST_I) {
      int slot = cslot[tid];
      float4 b = sboxes[slot];
      orows[r * 6 + 0] = b.x;
      orows[r * 6 + 1] = b.y;
      orows[r * 6 + 2] = b.z;
      orows[r * 6 + 3] = b.w;
      orows[r * 6 + 4] = (float)((slot >> 7) + 1);
      orows[r * 6 + 5] = __uint_as_float((unsigned int)(mk >> 32));
    }
  }
  __syncthreads();
  if (tid < 6 * MAX_INST_I) out[tid] = orows[tid];
}

extern "C" void kernel_launch(void* const* d_in, const int* in_sizes, int n_in,
                              void* d_out, int out_size, void* d_ws, size_t ws_size,
                              hipStream_t stream)
{
  const float* rois   = (const float*)d_in[0];
  const float* probs  = (const float*)d_in[1];
  const float* deltas = (const float*)d_in[2];
  const float* window = (const float*)d_in[3];
  float* out = (float*)d_out;

  char* ws = (char*)d_ws;
  float4* g_box   = (float4*)ws;                              // 80,000 B
  float*  g_score = (float*)(ws + 80000);                     // 20,000 B (16B-aligned)
  int*    g_cid   = (int*)(ws + 100000);                      // 20,000 B (16B-aligned)
  unsigned long long* skeys = (unsigned long long*)(ws + 120064);   // 80*128*8 = 81,920 B
  float4* sboxes  = (float4*)(ws + 202368);                   // 80*128*16 = 163,840 B

  det_stage1<<<(NROI * 64 + 255) / 256, 256, 0, stream>>>(
      rois, probs, deltas, window, g_box, g_score, g_cid);
  det_nms<<<NCLS - 1, 1024, 0, stream>>>(g_box, g_score, g_cid, skeys, sboxes);
  det_topk<<<1, 1024, 0, stream>>>(skeys, sboxes, out);
}

// Round 10
// 93.293 us; speedup vs baseline: 1.0406x; 1.0161x over previous
//
#include <hip/hip_runtime.h>
#include <math.h>

#define NROI 5000
#define NCLS 81
#define MIN_CONF_F 0.7f
#define MAX_INST_I 100
#define NMS_THR_F 0.3f
#define CAP2 128          // per-class cap (~8.5 sigma above Binomial(5000,1/81) mean 61.7)
#define SLOT 128          // survivor slots per class
#define HBINS 2048
#define CAPF 512          // candidate cap for final top-100
#define BMIN 0x3F333      // (bits of 0.7f) >> 12; scores in [0.7,1) -> bins [0,1229)

// ---------------- K1: per-ROI refine, one wave per ROI (5000 waves) ----------------
__global__ __launch_bounds__(256) void det_stage1(
    const float* __restrict__ rois, const float* __restrict__ probs,
    const float* __restrict__ deltas, const float* __restrict__ window,
    float4* __restrict__ g_box, float* __restrict__ g_score,
    int* __restrict__ g_cid)
{
  const int gtid = blockIdx.x * blockDim.x + threadIdx.x;
  const int i = gtid >> 6;        // ROI = global wave id
  const int lane = threadIdx.x & 63;
  if (i >= NROI) return;
  const float* p = probs + (size_t)i * NCLS;
  float v0 = p[lane];             // classes 0..63 (coalesced)
  unsigned long long key =
      ((unsigned long long)__float_as_uint(v0) << 32) | (unsigned)(255 - lane);
  if (lane < NCLS - 64) {         // classes 64..80
    float v1 = p[64 + lane];
    unsigned long long k1 =
        ((unsigned long long)__float_as_uint(v1) << 32) | (unsigned)(255 - (64 + lane));
    if (k1 > key) key = k1;
  }
  #pragma unroll
  for (int off = 32; off > 0; off >>= 1) {
    unsigned long long o = __shfl_xor(key, off, 64);
    if (o > key) key = o;
  }
  if (lane == 0) {
    int bc = 255 - (int)(key & 0xFFull);
    float best = __uint_as_float((unsigned)(key >> 32));
    const float* d = deltas + ((size_t)i * NCLS + bc) * 4;
    float dy = d[0]*0.1f, dx = d[1]*0.1f, dh = d[2]*0.2f, dwv = d[3]*0.2f;
    float y1 = rois[i*4+0], x1 = rois[i*4+1], y2 = rois[i*4+2], x2 = rois[i*4+3];
    float h = y2 - y1, w = x2 - x1;
    float cy = y1 + 0.5f*h, cx = x1 + 0.5f*w;
    cy = cy + dy*h; cx = cx + dx*w;
    h = h*expf(dh); w = w*expf(dwv);
    float ny1 = cy - 0.5f*h, nx1 = cx - 0.5f*w;
    float ny2 = ny1 + h, nx2 = nx1 + w;
    float wy1 = window[0], wx1 = window[1], wy2 = window[2], wx2 = window[3];
    ny1 = fminf(fmaxf(ny1, wy1), wy2);
    nx1 = fminf(fmaxf(nx1, wx1), wx2);
    ny2 = fminf(fmaxf(ny2, wy1), wy2);
    nx2 = fminf(fmaxf(nx2, wx1), wx2);
    g_box[i] = make_float4(ny1, nx1, ny2, nx2);
    g_score[i] = best;
    g_cid[i] = (bc > 0 && best >= MIN_CONF_F) ? bc : -1;   // -1 == invalid
  }
}

// ---------------- K2: per-class mask-NMS, fixed-slot survivor output ----------------
__global__ __launch_bounds__(1024) void det_nms(
    const float4* __restrict__ g_box, const float* __restrict__ g_score,
    const int* __restrict__ g_cid,
    int* __restrict__ svc, unsigned long long* __restrict__ skeys,
    float4* __restrict__ sboxes)
{
  const int c = blockIdx.x + 1;   // class 1..80
  const int tid = threadIdx.x;
  __shared__ int scnt;
  __shared__ unsigned long long keys[CAP2], skey[CAP2];
  __shared__ float by1[CAP2], bx1[CAP2], by2[CAP2], bx2[CAP2], barea[CAP2];
  __shared__ unsigned int mask[CAP2][4];
  __shared__ unsigned int keepw[4];
  if (tid == 0) scnt = 0;
  for (int q = tid; q < CAP2 * 4; q += 1024) ((unsigned int*)mask)[q] = 0u;
  __syncthreads();
  // collection: stream cid4 + score4 unconditionally (no load->atomic->load chain)
  const int4* cid4 = (const int4*)g_cid;
  const float4* sc4 = (const float4*)g_score;
  for (int v = tid; v < NROI / 4; v += 1024) {
    int4 cv = cid4[v];
    float4 sv = sc4[v];
    int base = v * 4;
    #pragma unroll
    for (int q = 0; q < 4; ++q) {
      int cq = (q == 0) ? cv.x : (q == 1) ? cv.y : (q == 2) ? cv.z : cv.w;
      float sq = (q == 0) ? sv.x : (q == 1) ? sv.y : (q == 2) ? sv.z : sv.w;
      if (cq == c) {
        int pos = atomicAdd(&scnt, 1);
        if (pos < CAP2)
          keys[pos] = ((unsigned long long)__float_as_uint(sq) << 32) |
                      (unsigned int)(0xFFFFFFFFu - (unsigned int)(base + q));
      }
    }
  }
  __syncthreads();
  int cnt = scnt < CAP2 ? scnt : CAP2;
  if (cnt > 0) {
    // rank-selection sort (keys unique): r = #greater -> skey[r]
    if (tid < cnt) {
      unsigned long long mk = keys[tid];
      int r = 0;
      for (int q = 0; q < cnt; ++q) r += (keys[q] > mk) ? 1 : 0;
      skey[r] = mk;
    }
    __syncthreads();
    if (tid < cnt) {
      int idx = (int)(0xFFFFFFFFu - (unsigned)(skey[tid] & 0xFFFFFFFFull));
      float4 b = g_box[idx];
      by1[tid] = b.x; bx1[tid] = b.y; by2[tid] = b.z; bx2[tid] = b.w;
      barea[tid] = fmaxf(b.z - b.x, 0.0f) * fmaxf(b.w - b.y, 0.0f);
    }
    __syncthreads();
    // pair-parallel IoU -> suppression bitmasks (bit k set in row j, k>j)
    int m = 1, lg = 0;
    while (m < cnt) { m <<= 1; ++lg; }
    int tot = m * m;
    for (int p = tid; p < tot; p += 1024) {
      int j = p >> lg, k = p & (m - 1);
      if (k > j && k < cnt) {
        float iy1 = fmaxf(by1[j], by1[k]);
        float ix1 = fmaxf(bx1[j], bx1[k]);
        float iy2 = fminf(by2[j], by2[k]);
        float ix2 = fminf(bx2[j], bx2[k]);
        float inter = fmaxf(iy2 - iy1, 0.0f) * fmaxf(ix2 - ix1, 0.0f);
        float uni = barea[j] + barea[k] - inter;
        float iou = (uni > 0.0f) ? inter / fmaxf(uni, 1e-12f) : 0.0f;
        if (iou > NMS_THR_F) atomicOr(&mask[j][k >> 5], 1u << (k & 31));
      }
    }
  }
  __syncthreads();
  // wave-0 register/shuffle greedy resolve (no LDS in the carry chain)
  if (tid < 64) {
    unsigned long long row_lo = 0, row_hi = 0, row2_lo = 0, row2_hi = 0;
    if (tid < cnt) {
      row_lo = (unsigned long long)mask[tid][0] | ((unsigned long long)mask[tid][1] << 32);
      row_hi = (unsigned long long)mask[tid][2] | ((unsigned long long)mask[tid][3] << 32);
    }
    if (tid + 64 < cnt) {
      row2_lo = (unsigned long long)mask[tid+64][0] | ((unsigned long long)mask[tid+64][1] << 32);
      row2_hi = (unsigned long long)mask[tid+64][2] | ((unsigned long long)mask[tid+64][3] << 32);
    }
    unsigned long long sup_lo = 0, sup_hi = 0, keep_lo = 0, keep_hi = 0;
    int kc = 0;
    for (int j = 0; j < cnt; ++j) {
      bool s = (j < 64) ? (((sup_lo >> j) & 1ull) != 0)
                        : (((sup_hi >> (j - 64)) & 1ull) != 0);
      if (!s && kc < MAX_INST_I) {
        if (j < 64) keep_lo |= 1ull << j; else keep_hi |= 1ull << (j - 64);
        ++kc;
        unsigned long long rl = (j < 64) ? row_lo : row2_lo;
        unsigned long long rh = (j < 64) ? row_hi : row2_hi;
        rl = __shfl(rl, j & 63, 64);
        rh = __shfl(rh, j & 63, 64);
        sup_lo |= rl; sup_hi |= rh;
      }
    }
    if (tid == 0) {
      keepw[0] = (unsigned)keep_lo; keepw[1] = (unsigned)(keep_lo >> 32);
      keepw[2] = (unsigned)keep_hi; keepw[3] = (unsigned)(keep_hi >> 32);
      svc[c - 1] = kc;              // plain store; kernel boundary publishes it
    }
  }
  __syncthreads();
  // survivors -> fixed per-class slots, ordered by keep rank
  if (tid < cnt) {
    unsigned long long klo = (unsigned long long)keepw[0] | ((unsigned long long)keepw[1] << 32);
    unsigned long long khi = (unsigned long long)keepw[2] | ((unsigned long long)keepw[3] << 32);
    bool kept = (tid < 64) ? ((klo >> tid) & 1ull) : ((khi >> (tid - 64)) & 1ull);
    if (kept) {
      int order = (tid < 64)
        ? __popcll(klo & ((1ull << tid) - 1ull))
        : __popcll(klo) + __popcll(khi & ((1ull << (tid - 64)) - 1ull));
      int slot = ((c - 1) << 7) + order;
      skeys[slot] = skey[tid];
      sboxes[slot] = make_float4(by1[tid], bx1[tid], by2[tid], bx2[tid]);
    }
  }
}

// ---------------- K3: top-100 over survivor slots ----------------
__global__ __launch_bounds__(1024) void det_topk(
    const int* __restrict__ svc, const unsigned long long* __restrict__ skeys,
    const float4* __restrict__ sboxes, float* __restrict__ out)
{
  const int tid = threadIdx.x;
  const int lane = tid & 63, wv = tid >> 6;
  __shared__ int svcnt[80];
  __shared__ int hist[HBINS];
  __shared__ unsigned long long cand[CAPF];
  __shared__ int cslot[CAPF];
  __shared__ float orows[6 * MAX_INST_I];
  __shared__ int wsum[16];
  __shared__ int fcnt, sR;
  if (tid < 80) svcnt[tid] = svc[tid];
  for (int b = tid; b < HBINS; b += 1024) hist[b] = 0;
  if (tid == 0) { fcnt = 0; sR = 1 << 30; }
  if (tid < 6 * MAX_INST_I) orows[tid] = 0.0f;
  __syncthreads();
  // histogram survivor scores (bits monotonic for positive floats)
  for (int s = tid; s < 80 * SLOT; s += 1024) {      // 10 rounds
    int c = s >> 7, k = s & (SLOT - 1);
    if (k < svcnt[c]) {
      unsigned int bits = (unsigned int)(skeys[s] >> 32);
      int b = (int)(bits >> 12) - BMIN;
      b = b < 0 ? 0 : (b > HBINS - 1 ? HBINS - 1 : b);
      atomicAdd(&hist[b], 1);
    }
  }
  __syncthreads();
  // suffix-count threshold: thread t owns rev positions 2t,2t+1 (bin HBINS-1-r)
  int a0 = hist[HBINS - 1 - 2 * tid];
  int a1 = hist[HBINS - 2 - 2 * tid];
  int val = a0 + a1;
  int incl = val;
  #pragma unroll
  for (int off = 1; off < 64; off <<= 1) {
    int nn = __shfl_up(incl, off, 64);
    if (lane >= off) incl += nn;
  }
  if (lane == 63) wsum[wv] = incl;
  __syncthreads();
  if (tid == 0) { int s = 0; for (int q = 0; q < 16; ++q) { s += wsum[q]; wsum[q] = s; } }
  __syncthreads();
  incl += (wv > 0) ? wsum[wv - 1] : 0;
  int excl = incl - val;
  if (excl + a0 >= MAX_INST_I) atomicMin(&sR, 2 * tid);
  else if (incl >= MAX_INST_I) atomicMin(&sR, 2 * tid + 1);
  __syncthreads();
  const int T = (sR >= HBINS) ? 0 : (HBINS - 1 - sR);   // total<100 -> collect all
  // collect candidates in bins >= T (contains the top-100)
  for (int s = tid; s < 80 * SLOT; s += 1024) {
    int c = s >> 7, k = s & (SLOT - 1);
    if (k < svcnt[c]) {
      unsigned long long key = skeys[s];
      unsigned int bits = (unsigned int)(key >> 32);
      int b = (int)(bits >> 12) - BMIN;
      b = b < 0 ? 0 : (b > HBINS - 1 ? HBINS - 1 : b);
      if (b >= T) {
        int pos = atomicAdd(&fcnt, 1);
        if (pos < CAPF) { cand[pos] = key; cslot[pos] = s; }
      }
    }
  }
  __syncthreads();
  int fc = fcnt < CAPF ? fcnt : CAPF;
  // rank placement (keys unique -> exact descending permutation)
  if (tid < fc) {
    unsigned long long mk = cand[tid];
    int r = 0;
    for (int q = 0; q < fc; ++q) r += (cand[q] > mk) ? 1 : 0;
    if (r < MAX_INST_I) {
      int slot = cslot[tid];
      float4 b = sboxes[slot];
      orows[r * 6 + 0] = b.x;
      orows[r * 6 + 1] = b.y;
      orows[r * 6 + 2] = b.z;
      orows[r * 6 + 3] = b.w;
      orows[r * 6 + 4] = (float)((slot >> 7) + 1);
      orows[r * 6 + 5] = __uint_as_float((unsigned int)(mk >> 32));
    }
  }
  __syncthreads();
  if (tid < 6 * MAX_INST_I) out[tid] = orows[tid];
}

extern "C" void kernel_launch(void* const* d_in, const int* in_sizes, int n_in,
                              void* d_out, int out_size, void* d_ws, size_t ws_size,
                              hipStream_t stream)
{
  const float* rois   = (const float*)d_in[0];
  const float* probs  = (const float*)d_in[1];
  const float* deltas = (const float*)d_in[2];
  const float* window = (const float*)d_in[3];
  float* out = (float*)d_out;

  char* ws = (char*)d_ws;
  float4* g_box   = (float4*)ws;                              // 80,000 B
  float*  g_score = (float*)(ws + 80000);                     // 20,000 B (16B-aligned)
  int*    g_cid   = (int*)(ws + 100000);                      // 20,000 B (16B-aligned)
  int*    svc     = (int*)(ws + 120000);                      // 320 B
  unsigned long long* skeys = (unsigned long long*)(ws + 120320);   // 80*128*8 = 81,920 B
  float4* sboxes  = (float4*)(ws + 202240);                   // 80*128*16 = 163,840 B

  det_stage1<<<(NROI * 64 + 255) / 256, 256, 0, stream>>>(
      rois, probs, deltas, window, g_box, g_score, g_cid);
  det_nms<<<NCLS - 1, 1024, 0, stream>>>(g_box, g_score, g_cid, svc, skeys, sboxes);
  det_topk<<<1, 1024, 0, stream>>>(svc, skeys, sboxes, out);
}